// Round 2
// baseline (1413.756 us; speedup 1.0000x reference)
//
#include <hip/hip_runtime.h>
#include <hip/hip_bf16.h>
#include <math.h>

#define HD 2048
#define ID 1024
#define NE 32
#define TOPK 4
#define NTOK 4096
#define NSLOT (NTOK*TOPK)

typedef __attribute__((ext_vector_type(4))) float f32x4;
typedef __attribute__((ext_vector_type(8))) short bf16x8;
typedef unsigned short u16;
typedef unsigned int u32;

typedef const void __attribute__((address_space(1)))* gas_p;
typedef void __attribute__((address_space(3)))* las_p;

static __device__ __forceinline__ void gload16(const void* g, void* l) {
  __builtin_amdgcn_global_load_lds((gas_p)g, (las_p)l, 16, 0, 0);
}

static __device__ __forceinline__ u16 f2bf(float f) {
  union { float f; u32 u; } v; v.f = f;
  u32 r = v.u + 0x7fffu + ((v.u >> 16) & 1u);
  return (u16)(r >> 16);
}

static __device__ __forceinline__ u32 packtrunc(float hi, float lo) {
  // (bf16(hi)<<16)|bf16(lo), truncation, 1 v_perm
  return __builtin_amdgcn_perm(__float_as_uint(hi), __float_as_uint(lo), 0x07060302u);
}

// ---------------- RMSNorm -> bf16 ----------------
__global__ __launch_bounds__(256) void k_rmsnorm(const float* __restrict__ x,
                                                 const float* __restrict__ w,
                                                 u16* __restrict__ xn) {
  int t = blockIdx.x, tid = threadIdx.x;
  const float* row = x + (size_t)t * HD;
  float4 v0 = ((const float4*)row)[tid*2+0];
  float4 v1 = ((const float4*)row)[tid*2+1];
  float ss = v0.x*v0.x+v0.y*v0.y+v0.z*v0.z+v0.w*v0.w
           + v1.x*v1.x+v1.y*v1.y+v1.z*v1.z+v1.w*v1.w;
  #pragma unroll
  for (int d=1; d<64; d<<=1) ss += __shfl_xor(ss, d);
  __shared__ float red[4];
  if ((tid&63)==0) red[tid>>6] = ss;
  __syncthreads();
  float rs = rsqrtf((red[0]+red[1]+red[2]+red[3]) * (1.0f/HD) + 1e-6f);
  const float* wp = w + tid*8;
  float a[8] = {v0.x,v0.y,v0.z,v0.w,v1.x,v1.y,v1.z,v1.w};
  uint4 o;
  o.x = (u32)f2bf(a[0]*rs*wp[0]) | ((u32)f2bf(a[1]*rs*wp[1])<<16);
  o.y = (u32)f2bf(a[2]*rs*wp[2]) | ((u32)f2bf(a[3]*rs*wp[3])<<16);
  o.z = (u32)f2bf(a[4]*rs*wp[4]) | ((u32)f2bf(a[5]*rs*wp[5])<<16);
  o.w = (u32)f2bf(a[6]*rs*wp[6]) | ((u32)f2bf(a[7]*rs*wp[7])<<16);
  ((uint4*)xn)[(size_t)t*(HD/8) + tid] = o;
}

// ---------------- Gate ----------------
__global__ __launch_bounds__(256) void k_gate(const float* __restrict__ x,
                                              const float* __restrict__ w,
                                              const float* __restrict__ gw,
                                              int* __restrict__ topk_id,
                                              float* __restrict__ topk_w,
                                              int* __restrict__ counts) {
  __shared__ float xs[HD];
  __shared__ float red[4];
  __shared__ float logits[NE];
  int t = blockIdx.x, tid = threadIdx.x;
  const float* row = x + (size_t)t*HD;
  float4 v0 = ((const float4*)row)[tid*2+0];
  float4 v1 = ((const float4*)row)[tid*2+1];
  float ss = v0.x*v0.x+v0.y*v0.y+v0.z*v0.z+v0.w*v0.w
           + v1.x*v1.x+v1.y*v1.y+v1.z*v1.z+v1.w*v1.w;
  #pragma unroll
  for (int d=1; d<64; d<<=1) ss += __shfl_xor(ss, d);
  if ((tid&63)==0) red[tid>>6] = ss;
  __syncthreads();
  float rs = 1.0f / sqrtf((red[0]+red[1]+red[2]+red[3]) * (1.0f/HD) + 1e-6f);
  const float* wp = w + tid*8;
  float a[8] = {v0.x,v0.y,v0.z,v0.w,v1.x,v1.y,v1.z,v1.w};
  #pragma unroll
  for (int j=0;j<8;++j) xs[tid*8+j] = a[j]*rs*wp[j];
  __syncthreads();
  int wave = tid>>6, lane = tid&63;
  for (int ei=0; ei<8; ++ei) {
    int e = wave*8 + ei;
    const float* g = gw + (size_t)e*HD;
    float s = 0.f;
    #pragma unroll
    for (int j=0;j<HD/64;++j) s += xs[lane + j*64] * g[lane + j*64];
    #pragma unroll
    for (int d=1; d<64; d<<=1) s += __shfl_xor(s, d);
    if (lane==0) logits[e] = s;
  }
  __syncthreads();
  if (tid==0) {
    float best[TOPK]; int bid[TOPK]; unsigned used = 0;
    for (int k2=0;k2<TOPK;++k2) {
      float bv = -1e30f; int bi = 0;
      for (int i2=0;i2<NE;++i2)
        if (!((used>>i2)&1u) && logits[i2] > bv) { bv = logits[i2]; bi = i2; }
      used |= 1u<<bi; best[k2] = bv; bid[k2] = bi;
    }
    float mx = best[0], sum = 0.f, wv[TOPK];
    for (int k2=0;k2<TOPK;++k2) { wv[k2] = expf(best[k2]-mx); sum += wv[k2]; }
    float inv = 1.f/sum;
    for (int k2=0;k2<TOPK;++k2) {
      topk_id[t*TOPK+k2] = bid[k2];
      topk_w[t*TOPK+k2] = wv[k2]*inv;
      atomicAdd(&counts[bid[k2]], 1);
    }
  }
}

__global__ void k_zero(int* counts, int* cursors) {
  int i = threadIdx.x;
  if (i < NE) { counts[i] = 0; cursors[i] = 0; }
}

__global__ void k_scan(const int* __restrict__ counts, int* __restrict__ starts) {
  if (threadIdx.x==0 && blockIdx.x==0) {
    int acc = 0;
    for (int e=0;e<NE;++e) { starts[e] = acc; acc += counts[e]; }
  }
}

__global__ __launch_bounds__(256) void k_dispatch(const int* __restrict__ topk_id,
                                                  const float* __restrict__ topk_w,
                                                  const int* __restrict__ starts,
                                                  int* __restrict__ cursors,
                                                  int* __restrict__ slot_tok,
                                                  float* __restrict__ slot_w) {
  int i = blockIdx.x*256 + threadIdx.x;
  int e = topk_id[i];
  int p = atomicAdd(&cursors[e], 1);
  int slot = starts[e] + p;
  slot_tok[slot] = i >> 2;
  slot_w[slot] = topk_w[i];
}

// ============ GEMM up (x @ [Wg|Wu]) + SwiGLU -> act bf16 ============
// BM=128 x 64 out cols (128 B cols: gate/up interleaved in 16-col groups)
// LDS: linear 16B slots; A slot s=(row, segp): addr s*16B, logical kseg = segp^((row>>1)&3)
//      B slot: col c -> q=c>>1, parity=c&1; addr = (q*4+segp)*16B + parity*4096B,
//      logical kseg = segp^((q>>1)&3). Writes lane-linear (conflict-free);
//      frag ds_read_b128 2-way (free).
template<bool INDEXED>
__global__ __launch_bounds__(256) void k_gemm_up(
    const u16* __restrict__ A, int lda, int kiter,
    const float* __restrict__ Bg, const float* __restrict__ Bu,
    size_t bstride, int ldb,
    const int* __restrict__ counts, const int* __restrict__ starts,
    const int* __restrict__ slot_tok,
    u16* __restrict__ actOut) {
  __shared__ u16 Al[2][4096];
  __shared__ u16 Bl[2][4096];
  __shared__ int rowL[128];
  int t = threadIdx.x;
  int n0 = blockIdx.x * 64;
  int m0 = blockIdx.y * 128;
  int e  = blockIdx.z;
  int M, rowbase;
  if (INDEXED) { M = counts[e]; rowbase = starts[e]; if (m0 >= M) return; }
  else { M = NTOK; rowbase = 0; }
  if (t < 128) {
    int m = m0 + t;
    rowL[t] = INDEXED ? slot_tok[rowbase + (m < M ? m : M-1)] : m;
  }
  __syncthreads();
  int kseg8 = (((t&3) ^ ((t>>3)&3)) << 3);        // logical k offset (elems/rows)
  const u16* an0 = A + (size_t)rowL[t>>2]*lda + kseg8;
  const u16* an1 = A + (size_t)rowL[(t>>2)+64]*lda + kseg8;
  // B: thread covers tile cols c0,c0+1 at k rows kseg8..kseg8+7
  int c0 = 2*((t>>2)&63);
  int og = ((c0>>5)<<4) | (c0&15);
  int isup = (c0>>4)&1;
  const float* bn = (isup ? Bu : Bg) + (size_t)e*bstride + (n0 + og) + (size_t)kseg8*ldb;

  int lane = t&63, wave = t>>6, wr = wave>>1, wc = wave&1;
  int l15 = lane&15, l4 = lane>>4;
  int aoff[4], boff[4];
  #pragma unroll
  for (int f=0; f<4; ++f) {
    int r = wr*64 + f*16 + l15;
    aoff[f] = r*32 + ((l4 ^ ((r>>1)&3))<<3);
    int c = wc*64 + f*16 + l15;
    boff[f] = (c>>1)*32 + ((c&1)<<11) + ((l4 ^ ((c>>2)&3))<<3);
  }
  f32x4 acc[4][4];
  #pragma unroll
  for (int fm=0;fm<4;++fm)
    #pragma unroll
    for (int fn=0;fn<4;++fn)
      acc[fm][fn] = (f32x4){0.f,0.f,0.f,0.f};

  // prologue: stage kt=0 into buf0
  float2 bv[8];
  gload16(an0, &Al[0][t*8]);
  gload16(an1, &Al[0][2048 + t*8]);
  #pragma unroll
  for (int j=0;j<8;++j) bv[j] = *(const float2*)(bn + (size_t)j*ldb);
  {
    uint4 w0, w1;
    w0.x = packtrunc(bv[1].x, bv[0].x); w0.y = packtrunc(bv[3].x, bv[2].x);
    w0.z = packtrunc(bv[5].x, bv[4].x); w0.w = packtrunc(bv[7].x, bv[6].x);
    w1.x = packtrunc(bv[1].y, bv[0].y); w1.y = packtrunc(bv[3].y, bv[2].y);
    w1.z = packtrunc(bv[5].y, bv[4].y); w1.w = packtrunc(bv[7].y, bv[6].y);
    *(uint4*)&Bl[0][t*8] = w0;
    *(uint4*)&Bl[0][2048 + t*8] = w1;
  }
  __syncthreads();

  int cur = 0;
  for (int kt = 0; kt < kiter; ++kt) {
    bool more = (kt+1 < kiter);
    if (more) {
      an0 += 32; an1 += 32; bn += (size_t)32*ldb;
      gload16(an0, &Al[cur^1][t*8]);
      gload16(an1, &Al[cur^1][2048 + t*8]);
      #pragma unroll
      for (int j=0;j<8;++j) bv[j] = *(const float2*)(bn + (size_t)j*ldb);
    }
    bf16x8 af[4], bfr[4];
    #pragma unroll
    for (int f=0; f<4; ++f) af[f] = *(const bf16x8*)&Al[cur][aoff[f]];
    #pragma unroll
    for (int f=0; f<4; ++f) bfr[f] = *(const bf16x8*)&Bl[cur][boff[f]];
    #pragma unroll
    for (int fm=0; fm<4; ++fm)
      #pragma unroll
      for (int fn=0; fn<4; ++fn)
        acc[fm][fn] = __builtin_amdgcn_mfma_f32_16x16x32_bf16(af[fm], bfr[fn], acc[fm][fn], 0,0,0);
    if (more) {
      uint4 w0, w1;
      w0.x = packtrunc(bv[1].x, bv[0].x); w0.y = packtrunc(bv[3].x, bv[2].x);
      w0.z = packtrunc(bv[5].x, bv[4].x); w0.w = packtrunc(bv[7].x, bv[6].x);
      w1.x = packtrunc(bv[1].y, bv[0].y); w1.y = packtrunc(bv[3].y, bv[2].y);
      w1.z = packtrunc(bv[5].y, bv[4].y); w1.w = packtrunc(bv[7].y, bv[6].y);
      *(uint4*)&Bl[cur^1][t*8] = w0;
      *(uint4*)&Bl[cur^1][2048 + t*8] = w1;
    }
    cur ^= 1;
    __syncthreads();
  }
  // epilogue: SwiGLU on (gate,up) fragment pairs
  #pragma unroll
  for (int fm=0; fm<4; ++fm) {
    #pragma unroll
    for (int fq=0; fq<2; ++fq) {
      f32x4 g = acc[fm][2*fq], u = acc[fm][2*fq+1];
      int col = n0 + (wc*2+fq)*16 + l15;
      #pragma unroll
      for (int r=0;r<4;++r) {
        int mloc = wr*64 + fm*16 + l4*4 + r;
        int m = m0 + mloc;
        if (m < M) {
          float gv = g[r];
          float av = gv / (1.f + expf(-gv)) * u[r];
          actOut[(size_t)(rowbase+m)*ID + col] = f2bf(av);
        }
      }
    }
  }
}

// ============ GEMM down (act @ W2) ============
template<bool INDEXED>
__global__ __launch_bounds__(256) void k_gemm_down(
    const u16* __restrict__ A, int lda, int kiter,
    const float* __restrict__ B,
    size_t bstride, int ldb,
    const int* __restrict__ counts, const int* __restrict__ starts,
    const int* __restrict__ slot_tok, const float* __restrict__ slot_w,
    const float* __restrict__ resid,
    float* __restrict__ out) {
  __shared__ u16 Al[2][4096];
  __shared__ u16 Bl[2][4096];
  __shared__ int rowL[128];
  __shared__ int tokL[128];
  __shared__ float wL[128];
  int t = threadIdx.x;
  int n0 = blockIdx.x * 128;
  int m0 = blockIdx.y * 128;
  int e  = blockIdx.z;
  int M, rowbase;
  if (INDEXED) { M = counts[e]; rowbase = starts[e]; if (m0 >= M) return; }
  else { M = NTOK; rowbase = 0; }
  if (t < 128) {
    int m = m0 + t;
    int cm = m < M ? m : M-1;
    rowL[t] = rowbase + cm;
    if (INDEXED) {
      tokL[t] = (m<M) ? slot_tok[rowbase+m] : 0;
      wL[t]   = (m<M) ? slot_w[rowbase+m]  : 0.f;
    }
  }
  __syncthreads();
  int kseg8 = (((t&3) ^ ((t>>3)&3)) << 3);
  const u16* an0 = A + (size_t)rowL[t>>2]*lda + kseg8;
  const u16* an1 = A + (size_t)rowL[(t>>2)+64]*lda + kseg8;
  int c0 = 2*((t>>2)&63);
  const float* bn = B + (size_t)e*bstride + (n0 + c0) + (size_t)kseg8*ldb;

  int lane = t&63, wave = t>>6, wr = wave>>1, wc = wave&1;
  int l15 = lane&15, l4 = lane>>4;
  int aoff[4], boff[4];
  #pragma unroll
  for (int f=0; f<4; ++f) {
    int r = wr*64 + f*16 + l15;
    aoff[f] = r*32 + ((l4 ^ ((r>>1)&3))<<3);
    int c = wc*64 + f*16 + l15;
    boff[f] = (c>>1)*32 + ((c&1)<<11) + ((l4 ^ ((c>>2)&3))<<3);
  }
  f32x4 acc[4][4];
  #pragma unroll
  for (int fm=0;fm<4;++fm)
    #pragma unroll
    for (int fn=0;fn<4;++fn)
      acc[fm][fn] = (f32x4){0.f,0.f,0.f,0.f};

  float2 bv[8];
  gload16(an0, &Al[0][t*8]);
  gload16(an1, &Al[0][2048 + t*8]);
  #pragma unroll
  for (int j=0;j<8;++j) bv[j] = *(const float2*)(bn + (size_t)j*ldb);
  {
    uint4 w0, w1;
    w0.x = packtrunc(bv[1].x, bv[0].x); w0.y = packtrunc(bv[3].x, bv[2].x);
    w0.z = packtrunc(bv[5].x, bv[4].x); w0.w = packtrunc(bv[7].x, bv[6].x);
    w1.x = packtrunc(bv[1].y, bv[0].y); w1.y = packtrunc(bv[3].y, bv[2].y);
    w1.z = packtrunc(bv[5].y, bv[4].y); w1.w = packtrunc(bv[7].y, bv[6].y);
    *(uint4*)&Bl[0][t*8] = w0;
    *(uint4*)&Bl[0][2048 + t*8] = w1;
  }
  __syncthreads();

  int cur = 0;
  for (int kt = 0; kt < kiter; ++kt) {
    bool more = (kt+1 < kiter);
    if (more) {
      an0 += 32; an1 += 32; bn += (size_t)32*ldb;
      gload16(an0, &Al[cur^1][t*8]);
      gload16(an1, &Al[cur^1][2048 + t*8]);
      #pragma unroll
      for (int j=0;j<8;++j) bv[j] = *(const float2*)(bn + (size_t)j*ldb);
    }
    bf16x8 af[4], bfr[4];
    #pragma unroll
    for (int f=0; f<4; ++f) af[f] = *(const bf16x8*)&Al[cur][aoff[f]];
    #pragma unroll
    for (int f=0; f<4; ++f) bfr[f] = *(const bf16x8*)&Bl[cur][boff[f]];
    #pragma unroll
    for (int fm=0; fm<4; ++fm)
      #pragma unroll
      for (int fn=0; fn<4; ++fn)
        acc[fm][fn] = __builtin_amdgcn_mfma_f32_16x16x32_bf16(af[fm], bfr[fn], acc[fm][fn], 0,0,0);
    if (more) {
      uint4 w0, w1;
      w0.x = packtrunc(bv[1].x, bv[0].x); w0.y = packtrunc(bv[3].x, bv[2].x);
      w0.z = packtrunc(bv[5].x, bv[4].x); w0.w = packtrunc(bv[7].x, bv[6].x);
      w1.x = packtrunc(bv[1].y, bv[0].y); w1.y = packtrunc(bv[3].y, bv[2].y);
      w1.z = packtrunc(bv[5].y, bv[4].y); w1.w = packtrunc(bv[7].y, bv[6].y);
      *(uint4*)&Bl[cur^1][t*8] = w0;
      *(uint4*)&Bl[cur^1][2048 + t*8] = w1;
    }
    cur ^= 1;
    __syncthreads();
  }
  #pragma unroll
  for (int fm=0; fm<4; ++fm) {
    #pragma unroll
    for (int fn=0; fn<4; ++fn) {
      f32x4 v = acc[fm][fn];
      int col = n0 + wc*64 + fn*16 + l15;
      #pragma unroll
      for (int r=0;r<4;++r) {
        int mloc = wr*64 + fm*16 + l4*4 + r;
        int m = m0 + mloc;
        if (m < M) {
          if (INDEXED) {
            atomicAdd(&out[(size_t)tokL[mloc]*HD + col], v[r]*wL[mloc]);
          } else {
            size_t o = (size_t)m*HD + col;
            out[o] = resid[o] + v[r];
          }
        }
      }
    }
  }
}

extern "C" void kernel_launch(void* const* d_in, const int* in_sizes, int n_in,
                              void* d_out, int out_size, void* d_ws, size_t ws_size,
                              hipStream_t stream) {
  const float* x    = (const float*)d_in[0];
  const float* nw   = (const float*)d_in[1];
  const float* gw   = (const float*)d_in[2];
  const float* w13  = (const float*)d_in[3];
  const float* w2   = (const float*)d_in[4];
  const float* sgw  = (const float*)d_in[5];
  const float* suw  = (const float*)d_in[6];
  const float* sdw  = (const float*)d_in[7];
  float* out = (float*)d_out;

  char* p = (char*)d_ws;
  u16* xn   = (u16*)p;    p += (size_t)NTOK*HD*2;
  u16* act  = (u16*)p;    p += (size_t)NSLOT*ID*2;
  u16* sact = (u16*)p;    p += (size_t)NTOK*ID*2;
  int*   topk_id  = (int*)p;   p += (size_t)NTOK*TOPK*4;
  float* topk_w   = (float*)p; p += (size_t)NTOK*TOPK*4;
  int*   slot_tok = (int*)p;   p += (size_t)NSLOT*4;
  float* slot_w   = (float*)p; p += (size_t)NSLOT*4;
  int*   counts   = (int*)p;   p += 64*4;
  int*   cursors  = (int*)p;   p += 64*4;
  int*   starts   = (int*)p;   p += 64*4;

  k_zero<<<1, 64, 0, stream>>>(counts, cursors);
  k_rmsnorm<<<NTOK, 256, 0, stream>>>(x, nw, xn);
  k_gate<<<NTOK, 256, 0, stream>>>(x, nw, gw, topk_id, topk_w, counts);
  k_scan<<<1, 1, 0, stream>>>(counts, starts);
  k_dispatch<<<NSLOT/256, 256, 0, stream>>>(topk_id, topk_w, starts, cursors, slot_tok, slot_w);

  // routed up-proj + swiglu
  k_gemm_up<true><<<dim3(ID/64, 8, NE), 256, 0, stream>>>(
      xn, HD, HD/32, w13, w13 + ID, (size_t)HD*2*ID, 2*ID, counts, starts, slot_tok, act);
  // shared up-proj + swiglu
  k_gemm_up<false><<<dim3(ID/64, NTOK/128, 1), 256, 0, stream>>>(
      xn, HD, HD/32, sgw, suw, (size_t)0, ID, nullptr, nullptr, nullptr, sact);
  // shared down-proj: out = residual + shared
  k_gemm_down<false><<<dim3(HD/128, NTOK/128, 1), 256, 0, stream>>>(
      sact, ID, ID/32, sdw, (size_t)0, HD, nullptr, nullptr, nullptr, nullptr, x, out);
  // routed down-proj: atomic weighted scatter-add into out
  k_gemm_down<true><<<dim3(HD/128, 8, NE), 256, 0, stream>>>(
      act, ID, ID/32, w2, (size_t)ID*HD, HD, counts, starts, slot_tok, slot_w, nullptr, out);
}

// Round 4
// 951.228 us; speedup vs baseline: 1.4862x; 1.4862x over previous
//
#include <hip/hip_runtime.h>
#include <hip/hip_bf16.h>
#include <math.h>

#define HD 2048
#define ID 1024
#define NE 32
#define TOPK 4
#define NTOK 4096
#define NSLOT (NTOK*TOPK)

typedef __attribute__((ext_vector_type(4))) float f32x4;
typedef __attribute__((ext_vector_type(8))) short bf16x8;
typedef unsigned short u16;
typedef unsigned int u32;

typedef const void __attribute__((address_space(1)))* gas_p;
typedef void __attribute__((address_space(3)))* las_p;

static __device__ __forceinline__ void gload16(const void* g, void* l) {
  __builtin_amdgcn_global_load_lds((gas_p)g, (las_p)l, 16, 0, 0);
}

static __device__ __forceinline__ u16 f2bf(float f) {
  union { float f; u32 u; } v; v.f = f;
  u32 r = v.u + 0x7fffu + ((v.u >> 16) & 1u);
  return (u16)(r >> 16);
}

// ---------------- transpose + fp32->bf16 convert ----------------
// src [R][C] fp32 -> dst [C][R] bf16 ; grid (C/64, R/64, nmat)
__global__ __launch_bounds__(256) void k_tcvt(const float* __restrict__ src,
                                              u16* __restrict__ dst,
                                              int R, int C) {
  __shared__ float tile[64][68];
  int t = threadIdx.x;
  size_t matoff = (size_t)blockIdx.z * R * C;
  const float* s = src + matoff;
  u16* d = dst + matoff;
  int c0 = blockIdx.x * 64, r0 = blockIdx.y * 64;
  int tx = t & 15, rr = t >> 4;
  #pragma unroll
  for (int i = 0; i < 4; ++i) {
    int r = rr + 16*i;
    float4 v = *(const float4*)(s + (size_t)(r0 + r)*C + c0 + tx*4);
    tile[r][tx*4+0] = v.x; tile[r][tx*4+1] = v.y;
    tile[r][tx*4+2] = v.z; tile[r][tx*4+3] = v.w;
  }
  __syncthreads();
  int orow = t >> 2, seg = t & 3;
  #pragma unroll
  for (int h = 0; h < 2; ++h) {       // two 8-elem chunks: k-rows seg*8.. and 32+seg*8..
    float f[8];
    #pragma unroll
    for (int j = 0; j < 8; ++j) f[j] = tile[h*32 + seg*8 + j][orow];
    uint4 o;
    o.x = (u32)f2bf(f[0]) | ((u32)f2bf(f[1])<<16);
    o.y = (u32)f2bf(f[2]) | ((u32)f2bf(f[3])<<16);
    o.z = (u32)f2bf(f[4]) | ((u32)f2bf(f[5])<<16);
    o.w = (u32)f2bf(f[6]) | ((u32)f2bf(f[7])<<16);
    *(uint4*)(d + (size_t)(c0 + orow)*R + r0 + h*32 + seg*8) = o;
  }
}

// ---------------- RMSNorm -> bf16 ----------------
__global__ __launch_bounds__(256) void k_rmsnorm(const float* __restrict__ x,
                                                 const float* __restrict__ w,
                                                 u16* __restrict__ xn) {
  int t = blockIdx.x, tid = threadIdx.x;
  const float* row = x + (size_t)t * HD;
  float4 v0 = ((const float4*)row)[tid*2+0];
  float4 v1 = ((const float4*)row)[tid*2+1];
  float ss = v0.x*v0.x+v0.y*v0.y+v0.z*v0.z+v0.w*v0.w
           + v1.x*v1.x+v1.y*v1.y+v1.z*v1.z+v1.w*v1.w;
  #pragma unroll
  for (int d=1; d<64; d<<=1) ss += __shfl_xor(ss, d);
  __shared__ float red[4];
  if ((tid&63)==0) red[tid>>6] = ss;
  __syncthreads();
  float rs = rsqrtf((red[0]+red[1]+red[2]+red[3]) * (1.0f/HD) + 1e-6f);
  const float* wp = w + tid*8;
  float a[8] = {v0.x,v0.y,v0.z,v0.w,v1.x,v1.y,v1.z,v1.w};
  uint4 o;
  o.x = (u32)f2bf(a[0]*rs*wp[0]) | ((u32)f2bf(a[1]*rs*wp[1])<<16);
  o.y = (u32)f2bf(a[2]*rs*wp[2]) | ((u32)f2bf(a[3]*rs*wp[3])<<16);
  o.z = (u32)f2bf(a[4]*rs*wp[4]) | ((u32)f2bf(a[5]*rs*wp[5])<<16);
  o.w = (u32)f2bf(a[6]*rs*wp[6]) | ((u32)f2bf(a[7]*rs*wp[7])<<16);
  ((uint4*)xn)[(size_t)t*(HD/8) + tid] = o;
}

// ---------------- Gate ----------------
__global__ __launch_bounds__(256) void k_gate(const float* __restrict__ x,
                                              const float* __restrict__ w,
                                              const float* __restrict__ gw,
                                              int* __restrict__ topk_id,
                                              float* __restrict__ topk_w,
                                              int* __restrict__ counts) {
  __shared__ float xs[HD];
  __shared__ float red[4];
  __shared__ float logits[NE];
  int t = blockIdx.x, tid = threadIdx.x;
  const float* row = x + (size_t)t*HD;
  float4 v0 = ((const float4*)row)[tid*2+0];
  float4 v1 = ((const float4*)row)[tid*2+1];
  float ss = v0.x*v0.x+v0.y*v0.y+v0.z*v0.z+v0.w*v0.w
           + v1.x*v1.x+v1.y*v1.y+v1.z*v1.z+v1.w*v1.w;
  #pragma unroll
  for (int d=1; d<64; d<<=1) ss += __shfl_xor(ss, d);
  if ((tid&63)==0) red[tid>>6] = ss;
  __syncthreads();
  float rs = 1.0f / sqrtf((red[0]+red[1]+red[2]+red[3]) * (1.0f/HD) + 1e-6f);
  const float* wp = w + tid*8;
  float a[8] = {v0.x,v0.y,v0.z,v0.w,v1.x,v1.y,v1.z,v1.w};
  #pragma unroll
  for (int j=0;j<8;++j) xs[tid*8+j] = a[j]*rs*wp[j];
  __syncthreads();
  int wave = tid>>6, lane = tid&63;
  for (int ei=0; ei<8; ++ei) {
    int e = wave*8 + ei;
    const float* g = gw + (size_t)e*HD;
    float s = 0.f;
    #pragma unroll
    for (int j=0;j<HD/64;++j) s += xs[lane + j*64] * g[lane + j*64];
    #pragma unroll
    for (int d=1; d<64; d<<=1) s += __shfl_xor(s, d);
    if (lane==0) logits[e] = s;
  }
  __syncthreads();
  if (tid==0) {
    float best[TOPK]; int bid[TOPK]; unsigned used = 0;
    for (int k2=0;k2<TOPK;++k2) {
      float bv = -1e30f; int bi = 0;
      for (int i2=0;i2<NE;++i2)
        if (!((used>>i2)&1u) && logits[i2] > bv) { bv = logits[i2]; bi = i2; }
      used |= 1u<<bi; best[k2] = bv; bid[k2] = bi;
    }
    float mx = best[0], sum = 0.f, wv[TOPK];
    for (int k2=0;k2<TOPK;++k2) { wv[k2] = expf(best[k2]-mx); sum += wv[k2]; }
    float inv = 1.f/sum;
    for (int k2=0;k2<TOPK;++k2) {
      topk_id[t*TOPK+k2] = bid[k2];
      topk_w[t*TOPK+k2] = wv[k2]*inv;
      atomicAdd(&counts[bid[k2]], 1);
    }
  }
}

__global__ void k_zero(int* counts, int* cursors) {
  int i = threadIdx.x;
  if (i < NE) { counts[i] = 0; cursors[i] = 0; }
}

__global__ void k_scan(const int* __restrict__ counts, int* __restrict__ starts) {
  if (threadIdx.x==0 && blockIdx.x==0) {
    int acc = 0;
    for (int e=0;e<NE;++e) { starts[e] = acc; acc += counts[e]; }
  }
}

__global__ __launch_bounds__(256) void k_dispatch(const int* __restrict__ topk_id,
                                                  const float* __restrict__ topk_w,
                                                  const int* __restrict__ starts,
                                                  int* __restrict__ cursors,
                                                  int* __restrict__ slot_tok,
                                                  float* __restrict__ slot_w) {
  int i = blockIdx.x*256 + threadIdx.x;
  int e = topk_id[i];
  int p = atomicAdd(&cursors[e], 1);
  int slot = starts[e] + p;
  slot_tok[slot] = i >> 2;
  slot_w[slot] = topk_w[i];
}

// ============ GEMM up (x @ [Wg|Wu]^T-layout) + SwiGLU -> act bf16 ============
// m97-style: both operands bf16 k-major, staged via global_load_lds w16.
// LDS slot s (16B): index = s>>2 (row/col), phys kseg = s&3,
// logical kseg = phys ^ ((idx>>1)&3). Frag reads 2-way (free).
// LDS cols 0..127 interleave gate/up in 16-col groups: isup=(c>>4)&1, og=((c>>5)<<4)|(c&15).
template<bool INDEXED>
__global__ __launch_bounds__(256) void k_gemm_up(
    const u16* __restrict__ A, int lda, int kiter,
    const u16* __restrict__ Bg, const u16* __restrict__ Bu, size_t bstride,
    const int* __restrict__ counts, const int* __restrict__ starts,
    const int* __restrict__ slot_tok,
    u16* __restrict__ actOut) {
  __shared__ u16 Al[4096];
  __shared__ u16 Bl[4096];
  __shared__ int rowL[128];
  int t = threadIdx.x;
  int n0 = blockIdx.x * 64;
  int m0 = blockIdx.y * 128;
  int e  = blockIdx.z;
  int M, rowbase;
  if (INDEXED) { M = counts[e]; rowbase = starts[e]; if (m0 >= M) return; }
  else { M = NTOK; rowbase = 0; }
  if (t < 128) {
    int m = m0 + t;
    rowL[t] = INDEXED ? slot_tok[rowbase + (m < M ? m : M-1)] : m;
  }
  __syncthreads();
  // A: slots t and t+256
  int r0i = t>>2, r1i = r0i + 64;
  int segA = ((t&3) ^ ((r0i>>1)&3)) << 3;
  const u16* srcA0 = A + (size_t)rowL[r0i]*lda + segA;
  const u16* srcA1 = A + (size_t)rowL[r1i]*lda + segA;
  // B: slots t and t+256 -> LDS cols c0=t>>2, c1=c0+64
  const u16* Bge = Bg + (INDEXED ? (size_t)e*bstride : 0);
  const u16* Bue = Bu + (INDEXED ? (size_t)e*bstride : 0);
  int c0 = t>>2, c1 = c0 + 64;
  int og0 = ((c0>>5)<<4)|(c0&15), og1 = ((c1>>5)<<4)|(c1&15);
  const u16* b0base = ((c0>>4)&1) ? Bue : Bge;
  const u16* b1base = ((c1>>4)&1) ? Bue : Bge;
  const u16* srcB0 = b0base + (size_t)(n0+og0)*lda + segA;  // segB == segA (same formula)
  const u16* srcB1 = b1base + (size_t)(n0+og1)*lda + segA;

  int lane = t&63, wave = t>>6, wr = wave>>1, wc = wave&1;
  int l15 = lane&15, l4 = lane>>4;
  int aoff[4], boff[4];
  #pragma unroll
  for (int f=0; f<4; ++f) {
    int r = wr*64 + f*16 + l15;
    aoff[f] = r*32 + ((l4 ^ ((r>>1)&3))<<3);
    int c = wc*64 + f*16 + l15;
    boff[f] = c*32 + ((l4 ^ ((c>>1)&3))<<3);
  }
  f32x4 acc[4][4];
  #pragma unroll
  for (int fm=0;fm<4;++fm)
    #pragma unroll
    for (int fn=0;fn<4;++fn)
      acc[fm][fn] = (f32x4){0.f,0.f,0.f,0.f};

  for (int kt = 0; kt < kiter; ++kt) {
    gload16(srcA0, &Al[(size_t)t*8]);
    gload16(srcA1, &Al[2048 + (size_t)t*8]);
    gload16(srcB0, &Bl[(size_t)t*8]);
    gload16(srcB1, &Bl[2048 + (size_t)t*8]);
    srcA0 += 32; srcA1 += 32; srcB0 += 32; srcB1 += 32;
    __syncthreads();
    bf16x8 af[4], bfr[4];
    #pragma unroll
    for (int f=0; f<4; ++f) af[f] = *(const bf16x8*)&Al[aoff[f]];
    #pragma unroll
    for (int f=0; f<4; ++f) bfr[f] = *(const bf16x8*)&Bl[boff[f]];
    #pragma unroll
    for (int fm=0; fm<4; ++fm)
      #pragma unroll
      for (int fn=0; fn<4; ++fn)
        acc[fm][fn] = __builtin_amdgcn_mfma_f32_16x16x32_bf16(af[fm], bfr[fn], acc[fm][fn], 0,0,0);
    __syncthreads();
  }
  // epilogue: SwiGLU on (gate,up) fragment pairs
  #pragma unroll
  for (int fm=0; fm<4; ++fm) {
    #pragma unroll
    for (int fq=0; fq<2; ++fq) {
      f32x4 g = acc[fm][2*fq], u = acc[fm][2*fq+1];
      int col = n0 + (wc*2+fq)*16 + l15;
      #pragma unroll
      for (int r=0;r<4;++r) {
        int mloc = wr*64 + fm*16 + l4*4 + r;
        int m = m0 + mloc;
        if (m < M) {
          float gv = g[r];
          float av = gv / (1.f + expf(-gv)) * u[r];
          actOut[(size_t)(rowbase+m)*ID + col] = f2bf(av);
        }
      }
    }
  }
}

// ============ GEMM down (act @ W2t) ============
template<bool INDEXED>
__global__ __launch_bounds__(256) void k_gemm_down(
    const u16* __restrict__ A, int lda, int kiter,
    const u16* __restrict__ Bt, size_t bstride,
    const int* __restrict__ counts, const int* __restrict__ starts,
    const int* __restrict__ slot_tok, const float* __restrict__ slot_w,
    const float* __restrict__ resid,
    float* __restrict__ out) {
  __shared__ u16 Al[4096];
  __shared__ u16 Bl[4096];
  __shared__ int tokL[128];
  __shared__ float wL[128];
  int t = threadIdx.x;
  int n0 = blockIdx.x * 128;
  int m0 = blockIdx.y * 128;
  int e  = blockIdx.z;
  int M, rowbase;
  if (INDEXED) { M = counts[e]; rowbase = starts[e]; if (m0 >= M) return; }
  else { M = NTOK; rowbase = 0; }
  if (INDEXED && t < 128) {
    int m = m0 + t;
    tokL[t] = (m<M) ? slot_tok[rowbase+m] : 0;
    wL[t]   = (m<M) ? slot_w[rowbase+m]  : 0.f;
  }
  if (INDEXED) __syncthreads();
  int r0i = t>>2, r1i = r0i + 64;
  int segA = ((t&3) ^ ((r0i>>1)&3)) << 3;
  int am0 = m0 + r0i, am1 = m0 + r1i;
  const u16* srcA0 = A + (size_t)(rowbase + (am0 < M ? am0 : M-1))*lda + segA;
  const u16* srcA1 = A + (size_t)(rowbase + (am1 < M ? am1 : M-1))*lda + segA;
  const u16* Be = Bt + (INDEXED ? (size_t)e*bstride : 0);
  const u16* srcB0 = Be + (size_t)(n0 + r0i)*lda + segA;
  const u16* srcB1 = Be + (size_t)(n0 + r1i)*lda + segA;

  int lane = t&63, wave = t>>6, wr = wave>>1, wc = wave&1;
  int l15 = lane&15, l4 = lane>>4;
  int aoff[4], boff[4];
  #pragma unroll
  for (int f=0; f<4; ++f) {
    int r = wr*64 + f*16 + l15;
    aoff[f] = r*32 + ((l4 ^ ((r>>1)&3))<<3);
    int c = wc*64 + f*16 + l15;
    boff[f] = c*32 + ((l4 ^ ((c>>1)&3))<<3);
  }
  f32x4 acc[4][4];
  #pragma unroll
  for (int fm=0;fm<4;++fm)
    #pragma unroll
    for (int fn=0;fn<4;++fn)
      acc[fm][fn] = (f32x4){0.f,0.f,0.f,0.f};

  for (int kt = 0; kt < kiter; ++kt) {
    gload16(srcA0, &Al[(size_t)t*8]);
    gload16(srcA1, &Al[2048 + (size_t)t*8]);
    gload16(srcB0, &Bl[(size_t)t*8]);
    gload16(srcB1, &Bl[2048 + (size_t)t*8]);
    srcA0 += 32; srcA1 += 32; srcB0 += 32; srcB1 += 32;
    __syncthreads();
    bf16x8 af[4], bfr[4];
    #pragma unroll
    for (int f=0; f<4; ++f) af[f] = *(const bf16x8*)&Al[aoff[f]];
    #pragma unroll
    for (int f=0; f<4; ++f) bfr[f] = *(const bf16x8*)&Bl[boff[f]];
    #pragma unroll
    for (int fm=0; fm<4; ++fm)
      #pragma unroll
      for (int fn=0; fn<4; ++fn)
        acc[fm][fn] = __builtin_amdgcn_mfma_f32_16x16x32_bf16(af[fm], bfr[fn], acc[fm][fn], 0,0,0);
    __syncthreads();
  }
  #pragma unroll
  for (int fm=0; fm<4; ++fm) {
    #pragma unroll
    for (int fn=0; fn<4; ++fn) {
      f32x4 v = acc[fm][fn];
      int col = n0 + wc*64 + fn*16 + l15;
      #pragma unroll
      for (int r=0;r<4;++r) {
        int mloc = wr*64 + fm*16 + l4*4 + r;
        int m = m0 + mloc;
        if (m < M) {
          if (INDEXED) {
            atomicAdd(&out[(size_t)tokL[mloc]*HD + col], v[r]*wL[mloc]);
          } else {
            size_t o = (size_t)m*HD + col;
            out[o] = resid[o] + v[r];
          }
        }
      }
    }
  }
}

extern "C" void kernel_launch(void* const* d_in, const int* in_sizes, int n_in,
                              void* d_out, int out_size, void* d_ws, size_t ws_size,
                              hipStream_t stream) {
  const float* x    = (const float*)d_in[0];
  const float* nw   = (const float*)d_in[1];
  const float* gw   = (const float*)d_in[2];
  const float* w13  = (const float*)d_in[3];
  const float* w2   = (const float*)d_in[4];
  const float* sgw  = (const float*)d_in[5];
  const float* suw  = (const float*)d_in[6];
  const float* sdw  = (const float*)d_in[7];
  float* out = (float*)d_out;

  char* p = (char*)d_ws;
  u16* w13t = (u16*)p;  p += (size_t)NE*2*ID*HD*2;   // [E][2I][H] bf16 (gate rows 0..I-1, up I..2I-1)
  u16* w2t  = (u16*)p;  p += (size_t)NE*HD*ID*2;     // [E][H][I] bf16
  u16* sgwt = (u16*)p;  p += (size_t)ID*HD*2;        // [I][H]
  u16* suwt = (u16*)p;  p += (size_t)ID*HD*2;        // [I][H]
  u16* sdwt = (u16*)p;  p += (size_t)HD*ID*2;        // [H][I]
  u16* xn   = (u16*)p;  p += (size_t)NTOK*HD*2;
  u16* act  = (u16*)p;  p += (size_t)NSLOT*ID*2;
  u16* sact = (u16*)p;  p += (size_t)NTOK*ID*2;
  int*   topk_id  = (int*)p;   p += (size_t)NTOK*TOPK*4;
  float* topk_w   = (float*)p; p += (size_t)NTOK*TOPK*4;
  int*   slot_tok = (int*)p;   p += (size_t)NSLOT*4;
  float* slot_w   = (float*)p; p += (size_t)NSLOT*4;
  int*   counts   = (int*)p;   p += 64*4;
  int*   cursors  = (int*)p;   p += 64*4;
  int*   starts   = (int*)p;   p += 64*4;

  k_zero<<<1, 64, 0, stream>>>(counts, cursors);
  k_rmsnorm<<<NTOK, 256, 0, stream>>>(x, nw, xn);
  k_gate<<<NTOK, 256, 0, stream>>>(x, nw, gw, topk_id, topk_w, counts);
  k_scan<<<1, 1, 0, stream>>>(counts, starts);
  k_dispatch<<<NSLOT/256, 256, 0, stream>>>(topk_id, topk_w, starts, cursors, slot_tok, slot_w);

  // weight transpose+convert
  k_tcvt<<<dim3(2*ID/64, HD/64, NE), 256, 0, stream>>>(w13, w13t, HD, 2*ID);
  k_tcvt<<<dim3(HD/64, ID/64, NE), 256, 0, stream>>>(w2, w2t, ID, HD);
  k_tcvt<<<dim3(ID/64, HD/64, 1), 256, 0, stream>>>(sgw, sgwt, HD, ID);
  k_tcvt<<<dim3(ID/64, HD/64, 1), 256, 0, stream>>>(suw, suwt, HD, ID);
  k_tcvt<<<dim3(HD/64, ID/64, 1), 256, 0, stream>>>(sdw, sdwt, ID, HD);

  // routed up-proj + swiglu
  k_gemm_up<true><<<dim3(ID/64, 8, NE), 256, 0, stream>>>(
      xn, HD, HD/32, w13t, w13t + (size_t)ID*HD, (size_t)2*ID*HD,
      counts, starts, slot_tok, act);
  // shared up-proj + swiglu
  k_gemm_up<false><<<dim3(ID/64, NTOK/128, 1), 256, 0, stream>>>(
      xn, HD, HD/32, sgwt, suwt, 0, nullptr, nullptr, nullptr, sact);
  // shared down-proj: out = residual + shared
  k_gemm_down<false><<<dim3(HD/128, NTOK/128, 1), 256, 0, stream>>>(
      sact, ID, ID/32, sdwt, 0, nullptr, nullptr, nullptr, nullptr, x, out);
  // routed down-proj: atomic weighted scatter-add into out
  k_gemm_down<true><<<dim3(HD/128, 8, NE), 256, 0, stream>>>(
      act, ID, ID/32, w2t, (size_t)HD*ID, counts, starts, slot_tok, slot_w, nullptr, out);
}

// Round 5
// 867.180 us; speedup vs baseline: 1.6303x; 1.0969x over previous
//
#include <hip/hip_runtime.h>
#include <hip/hip_bf16.h>
#include <math.h>

#define HD 2048
#define ID 1024
#define NE 32
#define TOPK 4
#define NTOK 4096
#define NSLOT (NTOK*TOPK)

typedef __attribute__((ext_vector_type(4))) float f32x4;
typedef __attribute__((ext_vector_type(8))) short bf16x8;
typedef unsigned short u16;
typedef unsigned int u32;

typedef const void __attribute__((address_space(1)))* gas_p;
typedef void __attribute__((address_space(3)))* las_p;

static __device__ __forceinline__ void gload16(const void* g, void* l) {
  __builtin_amdgcn_global_load_lds((gas_p)g, (las_p)l, 16, 0, 0);
}

static __device__ __forceinline__ u16 f2bf(float f) {
  union { float f; u32 u; } v; v.f = f;
  u32 r = v.u + 0x7fffu + ((v.u >> 16) & 1u);
  return (u16)(r >> 16);
}

// (bf16(hi)<<16) | bf16(lo), RNE, single instruction
static __device__ __forceinline__ u32 cvtpk(float lo, float hi) {
  u32 r;
  asm("v_cvt_pk_bf16_f32 %0, %1, %2" : "=v"(r) : "v"(lo), "v"(hi));
  return r;
}

// ---------------- RMSNorm -> bf16 ----------------
__global__ __launch_bounds__(256) void k_rmsnorm(const float* __restrict__ x,
                                                 const float* __restrict__ w,
                                                 u16* __restrict__ xn) {
  int t = blockIdx.x, tid = threadIdx.x;
  const float* row = x + (size_t)t * HD;
  float4 v0 = ((const float4*)row)[tid*2+0];
  float4 v1 = ((const float4*)row)[tid*2+1];
  float ss = v0.x*v0.x+v0.y*v0.y+v0.z*v0.z+v0.w*v0.w
           + v1.x*v1.x+v1.y*v1.y+v1.z*v1.z+v1.w*v1.w;
  #pragma unroll
  for (int d=1; d<64; d<<=1) ss += __shfl_xor(ss, d);
  __shared__ float red[4];
  if ((tid&63)==0) red[tid>>6] = ss;
  __syncthreads();
  float rs = rsqrtf((red[0]+red[1]+red[2]+red[3]) * (1.0f/HD) + 1e-6f);
  const float* wp = w + tid*8;
  float a[8] = {v0.x,v0.y,v0.z,v0.w,v1.x,v1.y,v1.z,v1.w};
  uint4 o;
  o.x = (u32)f2bf(a[0]*rs*wp[0]) | ((u32)f2bf(a[1]*rs*wp[1])<<16);
  o.y = (u32)f2bf(a[2]*rs*wp[2]) | ((u32)f2bf(a[3]*rs*wp[3])<<16);
  o.z = (u32)f2bf(a[4]*rs*wp[4]) | ((u32)f2bf(a[5]*rs*wp[5])<<16);
  o.w = (u32)f2bf(a[6]*rs*wp[6]) | ((u32)f2bf(a[7]*rs*wp[7])<<16);
  ((uint4*)xn)[(size_t)t*(HD/8) + tid] = o;
}

// ---------------- Gate ----------------
__global__ __launch_bounds__(256) void k_gate(const float* __restrict__ x,
                                              const float* __restrict__ w,
                                              const float* __restrict__ gw,
                                              int* __restrict__ topk_id,
                                              float* __restrict__ topk_w,
                                              int* __restrict__ counts) {
  __shared__ float xs[HD];
  __shared__ float red[4];
  __shared__ float logits[NE];
  int t = blockIdx.x, tid = threadIdx.x;
  const float* row = x + (size_t)t*HD;
  float4 v0 = ((const float4*)row)[tid*2+0];
  float4 v1 = ((const float4*)row)[tid*2+1];
  float ss = v0.x*v0.x+v0.y*v0.y+v0.z*v0.z+v0.w*v0.w
           + v1.x*v1.x+v1.y*v1.y+v1.z*v1.z+v1.w*v1.w;
  #pragma unroll
  for (int d=1; d<64; d<<=1) ss += __shfl_xor(ss, d);
  if ((tid&63)==0) red[tid>>6] = ss;
  __syncthreads();
  float rs = 1.0f / sqrtf((red[0]+red[1]+red[2]+red[3]) * (1.0f/HD) + 1e-6f);
  const float* wp = w + tid*8;
  float a[8] = {v0.x,v0.y,v0.z,v0.w,v1.x,v1.y,v1.z,v1.w};
  #pragma unroll
  for (int j=0;j<8;++j) xs[tid*8+j] = a[j]*rs*wp[j];
  __syncthreads();
  int wave = tid>>6, lane = tid&63;
  for (int ei=0; ei<8; ++ei) {
    int e = wave*8 + ei;
    const float* g = gw + (size_t)e*HD;
    float s = 0.f;
    #pragma unroll
    for (int j=0;j<HD/64;++j) s += xs[lane + j*64] * g[lane + j*64];
    #pragma unroll
    for (int d=1; d<64; d<<=1) s += __shfl_xor(s, d);
    if (lane==0) logits[e] = s;
  }
  __syncthreads();
  if (tid==0) {
    float best[TOPK]; int bid[TOPK]; unsigned used = 0;
    for (int k2=0;k2<TOPK;++k2) {
      float bv = -1e30f; int bi = 0;
      for (int i2=0;i2<NE;++i2)
        if (!((used>>i2)&1u) && logits[i2] > bv) { bv = logits[i2]; bi = i2; }
      used |= 1u<<bi; best[k2] = bv; bid[k2] = bi;
    }
    float mx = best[0], sum = 0.f, wv[TOPK];
    for (int k2=0;k2<TOPK;++k2) { wv[k2] = expf(best[k2]-mx); sum += wv[k2]; }
    float inv = 1.f/sum;
    for (int k2=0;k2<TOPK;++k2) {
      topk_id[t*TOPK+k2] = bid[k2];
      topk_w[t*TOPK+k2] = wv[k2]*inv;
      atomicAdd(&counts[bid[k2]], 1);
    }
  }
}

__global__ void k_zero(int* counts, int* cursors) {
  int i = threadIdx.x;
  if (i < NE) { counts[i] = 0; cursors[i] = 0; }
}

__global__ void k_scan(const int* __restrict__ counts, int* __restrict__ starts) {
  if (threadIdx.x==0 && blockIdx.x==0) {
    int acc = 0;
    for (int e=0;e<NE;++e) { starts[e] = acc; acc += counts[e]; }
  }
}

__global__ __launch_bounds__(256) void k_dispatch(const int* __restrict__ topk_id,
                                                  const float* __restrict__ topk_w,
                                                  const int* __restrict__ starts,
                                                  int* __restrict__ cursors,
                                                  int* __restrict__ slot_tok,
                                                  float* __restrict__ slot_w) {
  int i = blockIdx.x*256 + threadIdx.x;
  int e = topk_id[i];
  int p = atomicAdd(&cursors[e], 1);
  int slot = starts[e] + p;
  slot_tok[slot] = i >> 2;
  slot_w[slot] = topk_w[i];
}

// ============ GEMM up (x @ [Wg|Wu]) + SwiGLU, fp32 B converted in-kernel ============
// A (bf16, k-major) via global_load_lds: slot s(16B): idx=s>>2, phys kseg=s&3,
//   logical kseg = phys ^ ((idx>>1)&3).
// B (fp32 [k][n]) via coalesced float4 row loads -> cvt_pk -> col-major LDS
//   [128 staged cols][32 k], byte addr = sc*64 + (kq ^ ((sc>>2)&6))*8 (kq = k>>2).
// Staged cols interleave gate/up in 16-col groups: isup=(sc>>4)&1, src = ((sc>>5)<<4)|(sc&15).
template<bool INDEXED>
__global__ __launch_bounds__(256) void k_gemm_up(
    const u16* __restrict__ A, int lda, int kiter,
    const float* __restrict__ Bg, const float* __restrict__ Bu,
    size_t bstride, int ldb,
    const int* __restrict__ counts, const int* __restrict__ starts,
    const int* __restrict__ slot_tok,
    u16* __restrict__ actOut) {
  __shared__ u16 Al[2][4096];
  __shared__ u16 Bl[2][4096];
  __shared__ int rowL[128];
  int t = threadIdx.x;
  int n0 = blockIdx.x * 64;
  int m0 = blockIdx.y * 128;
  int e  = blockIdx.z;
  int M, rowbase;
  if (INDEXED) { M = counts[e]; rowbase = starts[e]; if (m0 >= M) return; }
  else { M = NTOK; rowbase = 0; }
  if (t < 128) {
    int m = m0 + t;
    rowL[t] = INDEXED ? slot_tok[rowbase + (m < M ? m : M-1)] : m;
  }
  __syncthreads();
  // A staging (slots t, t+256)
  int r0i = t>>2, r1i = r0i + 64;
  int segA = ((t&3) ^ ((r0i>>1)&3)) << 3;
  const u16* srcA0 = A + (size_t)rowL[r0i]*lda + segA;
  const u16* srcA1 = A + (size_t)rowL[r1i]*lda + segA;
  // B staging: thread covers staged cols sc4..sc4+3, k rows kb..kb+3
  int sc4 = (t&31)*4;            // staged col base (4-aligned, one 16-group)
  int kbq = t>>5;                // 0..7  (k quad)
  int isup = (sc4>>4)&1;
  int srccol = n0 + ((sc4>>5)<<4) + (sc4&15);
  const float* bsrc = (isup ? Bu : Bg) + (INDEXED ? (size_t)e*bstride : 0)
                    + (size_t)(kbq*4)*ldb + srccol;
  int esw = (sc4>>2)&6;          // even XOR swizzle (preserves b128 contiguity)
  int bwidx = sc4*32 + (kbq ^ esw)*4;   // u16 index of first col's k-quad

  int lane = t&63, wave = t>>6, wr = wave>>1, wc = wave&1;
  int l15 = lane&15, l4 = lane>>4;
  int aoff[4], boff[4];
  #pragma unroll
  for (int f=0; f<4; ++f) {
    int r = wr*64 + f*16 + l15;
    aoff[f] = r*32 + ((l4 ^ ((r>>1)&3))<<3);
    int c = wc*64 + f*16 + l15;
    boff[f] = c*32 + ((2*l4) ^ ((c>>2)&6))*4;
  }
  f32x4 acc[4][4];
  #pragma unroll
  for (int fm=0;fm<4;++fm)
    #pragma unroll
    for (int fn=0;fn<4;++fn)
      acc[fm][fn] = (f32x4){0.f,0.f,0.f,0.f};

  // prologue: stage kt=0
  float4 bv[4];
  gload16(srcA0, &Al[0][t*8]);
  gload16(srcA1, &Al[0][2048 + t*8]);
  #pragma unroll
  for (int i=0;i<4;++i) bv[i] = *(const float4*)(bsrc + (size_t)i*ldb);
  srcA0 += 32; srcA1 += 32; bsrc += (size_t)32*ldb;
  {
    const float* f0 = (const float*)&bv[0];
    const float* f1 = (const float*)&bv[1];
    const float* f2 = (const float*)&bv[2];
    const float* f3 = (const float*)&bv[3];
    #pragma unroll
    for (int j=0;j<4;++j) {
      uint2 wv; wv.x = cvtpk(f0[j], f1[j]); wv.y = cvtpk(f2[j], f3[j]);
      *(uint2*)&Bl[0][bwidx + j*32] = wv;
    }
  }
  __syncthreads();

  int cur = 0;
  for (int kt = 0; kt < kiter; ++kt) {
    bool more = (kt+1 < kiter);
    if (more) {
      gload16(srcA0, &Al[cur^1][t*8]);
      gload16(srcA1, &Al[cur^1][2048 + t*8]);
      #pragma unroll
      for (int i=0;i<4;++i) bv[i] = *(const float4*)(bsrc + (size_t)i*ldb);
      srcA0 += 32; srcA1 += 32; bsrc += (size_t)32*ldb;
    }
    bf16x8 af[4], bfr[4];
    #pragma unroll
    for (int f=0; f<4; ++f) af[f] = *(const bf16x8*)&Al[cur][aoff[f]];
    #pragma unroll
    for (int f=0; f<4; ++f) bfr[f] = *(const bf16x8*)&Bl[cur][boff[f]];
    #pragma unroll
    for (int fm=0; fm<4; ++fm)
      #pragma unroll
      for (int fn=0; fn<4; ++fn)
        acc[fm][fn] = __builtin_amdgcn_mfma_f32_16x16x32_bf16(af[fm], bfr[fn], acc[fm][fn], 0,0,0);
    if (more) {
      const float* f0 = (const float*)&bv[0];
      const float* f1 = (const float*)&bv[1];
      const float* f2 = (const float*)&bv[2];
      const float* f3 = (const float*)&bv[3];
      #pragma unroll
      for (int j=0;j<4;++j) {
        uint2 wv; wv.x = cvtpk(f0[j], f1[j]); wv.y = cvtpk(f2[j], f3[j]);
        *(uint2*)&Bl[cur^1][bwidx + j*32] = wv;
      }
    }
    cur ^= 1;
    __syncthreads();
  }
  // epilogue: SwiGLU on (gate,up) fragment pairs
  #pragma unroll
  for (int fm=0; fm<4; ++fm) {
    #pragma unroll
    for (int fq=0; fq<2; ++fq) {
      f32x4 g = acc[fm][2*fq], u = acc[fm][2*fq+1];
      int col = n0 + (wc*2+fq)*16 + l15;
      #pragma unroll
      for (int r=0;r<4;++r) {
        int mloc = wr*64 + fm*16 + l4*4 + r;
        int m = m0 + mloc;
        if (m < M) {
          float gv = g[r];
          float av = gv / (1.f + expf(-gv)) * u[r];
          actOut[(size_t)(rowbase+m)*ID + col] = f2bf(av);
        }
      }
    }
  }
}

// ============ GEMM down (act @ W2), fp32 B converted in-kernel ============
template<bool INDEXED>
__global__ __launch_bounds__(256) void k_gemm_down(
    const u16* __restrict__ A, int lda, int kiter,
    const float* __restrict__ B, size_t bstride, int ldb,
    const int* __restrict__ counts, const int* __restrict__ starts,
    const int* __restrict__ slot_tok, const float* __restrict__ slot_w,
    const float* __restrict__ resid,
    float* __restrict__ out) {
  __shared__ u16 Al[2][4096];
  __shared__ u16 Bl[2][4096];
  __shared__ int tokL[128];
  __shared__ float wL[128];
  int t = threadIdx.x;
  int n0 = blockIdx.x * 128;
  int m0 = blockIdx.y * 128;
  int e  = blockIdx.z;
  int M, rowbase;
  if (INDEXED) { M = counts[e]; rowbase = starts[e]; if (m0 >= M) return; }
  else { M = NTOK; rowbase = 0; }
  if (INDEXED && t < 128) {
    int m = m0 + t;
    tokL[t] = (m<M) ? slot_tok[rowbase+m] : 0;
    wL[t]   = (m<M) ? slot_w[rowbase+m]  : 0.f;
  }
  if (INDEXED) __syncthreads();
  int r0i = t>>2, r1i = r0i + 64;
  int segA = ((t&3) ^ ((r0i>>1)&3)) << 3;
  int am0 = m0 + r0i, am1 = m0 + r1i;
  const u16* srcA0 = A + (size_t)(rowbase + (am0 < M ? am0 : M-1))*lda + segA;
  const u16* srcA1 = A + (size_t)(rowbase + (am1 < M ? am1 : M-1))*lda + segA;
  // B staging
  int sc4 = (t&31)*4;
  int kbq = t>>5;
  const float* bsrc = B + (INDEXED ? (size_t)e*bstride : 0)
                    + (size_t)(kbq*4)*ldb + (n0 + sc4);
  int esw = (sc4>>2)&6;
  int bwidx = sc4*32 + (kbq ^ esw)*4;

  int lane = t&63, wave = t>>6, wr = wave>>1, wc = wave&1;
  int l15 = lane&15, l4 = lane>>4;
  int aoff[4], boff[4];
  #pragma unroll
  for (int f=0; f<4; ++f) {
    int r = wr*64 + f*16 + l15;
    aoff[f] = r*32 + ((l4 ^ ((r>>1)&3))<<3);
    int c = wc*64 + f*16 + l15;
    boff[f] = c*32 + ((2*l4) ^ ((c>>2)&6))*4;
  }
  f32x4 acc[4][4];
  #pragma unroll
  for (int fm=0;fm<4;++fm)
    #pragma unroll
    for (int fn=0;fn<4;++fn)
      acc[fm][fn] = (f32x4){0.f,0.f,0.f,0.f};

  float4 bv[4];
  gload16(srcA0, &Al[0][t*8]);
  gload16(srcA1, &Al[0][2048 + t*8]);
  #pragma unroll
  for (int i=0;i<4;++i) bv[i] = *(const float4*)(bsrc + (size_t)i*ldb);
  srcA0 += 32; srcA1 += 32; bsrc += (size_t)32*ldb;
  {
    const float* f0 = (const float*)&bv[0];
    const float* f1 = (const float*)&bv[1];
    const float* f2 = (const float*)&bv[2];
    const float* f3 = (const float*)&bv[3];
    #pragma unroll
    for (int j=0;j<4;++j) {
      uint2 wv; wv.x = cvtpk(f0[j], f1[j]); wv.y = cvtpk(f2[j], f3[j]);
      *(uint2*)&Bl[0][bwidx + j*32] = wv;
    }
  }
  __syncthreads();

  int cur = 0;
  for (int kt = 0; kt < kiter; ++kt) {
    bool more = (kt+1 < kiter);
    if (more) {
      gload16(srcA0, &Al[cur^1][t*8]);
      gload16(srcA1, &Al[cur^1][2048 + t*8]);
      #pragma unroll
      for (int i=0;i<4;++i) bv[i] = *(const float4*)(bsrc + (size_t)i*ldb);
      srcA0 += 32; srcA1 += 32; bsrc += (size_t)32*ldb;
    }
    bf16x8 af[4], bfr[4];
    #pragma unroll
    for (int f=0; f<4; ++f) af[f] = *(const bf16x8*)&Al[cur][aoff[f]];
    #pragma unroll
    for (int f=0; f<4; ++f) bfr[f] = *(const bf16x8*)&Bl[cur][boff[f]];
    #pragma unroll
    for (int fm=0; fm<4; ++fm)
      #pragma unroll
      for (int fn=0; fn<4; ++fn)
        acc[fm][fn] = __builtin_amdgcn_mfma_f32_16x16x32_bf16(af[fm], bfr[fn], acc[fm][fn], 0,0,0);
    if (more) {
      const float* f0 = (const float*)&bv[0];
      const float* f1 = (const float*)&bv[1];
      const float* f2 = (const float*)&bv[2];
      const float* f3 = (const float*)&bv[3];
      #pragma unroll
      for (int j=0;j<4;++j) {
        uint2 wv; wv.x = cvtpk(f0[j], f1[j]); wv.y = cvtpk(f2[j], f3[j]);
        *(uint2*)&Bl[cur^1][bwidx + j*32] = wv;
      }
    }
    cur ^= 1;
    __syncthreads();
  }
  #pragma unroll
  for (int fm=0; fm<4; ++fm) {
    #pragma unroll
    for (int fn=0; fn<4; ++fn) {
      f32x4 v = acc[fm][fn];
      int col = n0 + wc*64 + fn*16 + l15;
      #pragma unroll
      for (int r=0;r<4;++r) {
        int mloc = wr*64 + fm*16 + l4*4 + r;
        int m = m0 + mloc;
        if (m < M) {
          if (INDEXED) {
            atomicAdd(&out[(size_t)tokL[mloc]*HD + col], v[r]*wL[mloc]);
          } else {
            size_t o = (size_t)m*HD + col;
            out[o] = resid[o] + v[r];
          }
        }
      }
    }
  }
}

extern "C" void kernel_launch(void* const* d_in, const int* in_sizes, int n_in,
                              void* d_out, int out_size, void* d_ws, size_t ws_size,
                              hipStream_t stream) {
  const float* x    = (const float*)d_in[0];
  const float* nw   = (const float*)d_in[1];
  const float* gw   = (const float*)d_in[2];
  const float* w13  = (const float*)d_in[3];
  const float* w2   = (const float*)d_in[4];
  const float* sgw  = (const float*)d_in[5];
  const float* suw  = (const float*)d_in[6];
  const float* sdw  = (const float*)d_in[7];
  float* out = (float*)d_out;

  char* p = (char*)d_ws;
  u16* xn   = (u16*)p;  p += (size_t)NTOK*HD*2;
  u16* act  = (u16*)p;  p += (size_t)NSLOT*ID*2;
  u16* sact = (u16*)p;  p += (size_t)NTOK*ID*2;
  int*   topk_id  = (int*)p;   p += (size_t)NTOK*TOPK*4;
  float* topk_w   = (float*)p; p += (size_t)NTOK*TOPK*4;
  int*   slot_tok = (int*)p;   p += (size_t)NSLOT*4;
  float* slot_w   = (float*)p; p += (size_t)NSLOT*4;
  int*   counts   = (int*)p;   p += 64*4;
  int*   cursors  = (int*)p;   p += 64*4;
  int*   starts   = (int*)p;   p += 64*4;

  k_zero<<<1, 64, 0, stream>>>(counts, cursors);
  k_rmsnorm<<<NTOK, 256, 0, stream>>>(x, nw, xn);
  k_gate<<<NTOK, 256, 0, stream>>>(x, nw, gw, topk_id, topk_w, counts);
  k_scan<<<1, 1, 0, stream>>>(counts, starts);
  k_dispatch<<<NSLOT/256, 256, 0, stream>>>(topk_id, topk_w, starts, cursors, slot_tok, slot_w);

  // routed up-proj + swiglu (B = w13 fp32, gate cols [0,I), up cols [I,2I))
  k_gemm_up<true><<<dim3(ID/64, 8, NE), 256, 0, stream>>>(
      xn, HD, HD/32, w13, w13 + ID, (size_t)HD*2*ID, 2*ID,
      counts, starts, slot_tok, act);
  // shared up-proj + swiglu
  k_gemm_up<false><<<dim3(ID/64, NTOK/128, 1), 256, 0, stream>>>(
      xn, HD, HD/32, sgw, suw, 0, ID, nullptr, nullptr, nullptr, sact);
  // shared down-proj: out = residual + shared
  k_gemm_down<false><<<dim3(HD/128, NTOK/128, 1), 256, 0, stream>>>(
      sact, ID, ID/32, sdw, 0, HD, nullptr, nullptr, nullptr, nullptr, x, out);
  // routed down-proj: atomic weighted scatter-add into out
  k_gemm_down<true><<<dim3(HD/128, 8, NE), 256, 0, stream>>>(
      act, ID, ID/32, w2, (size_t)ID*HD, HD, counts, starts, slot_tok, slot_w, nullptr, out);
}

// Round 6
// 792.156 us; speedup vs baseline: 1.7847x; 1.0947x over previous
//
#include <hip/hip_runtime.h>
#include <hip/hip_bf16.h>
#include <math.h>

#define HD 2048
#define ID 1024
#define NE 32
#define TOPK 4
#define NTOK 4096
#define NSLOT (NTOK*TOPK)

typedef __attribute__((ext_vector_type(4))) float f32x4;
typedef __attribute__((ext_vector_type(8))) short bf16x8;
typedef unsigned short u16;
typedef unsigned int u32;

union U32x4BF { uint4 u; bf16x8 h; };

static __device__ __forceinline__ u16 f2bf(float f) {
  union { float f; u32 u; } v; v.f = f;
  u32 r = v.u + 0x7fffu + ((v.u >> 16) & 1u);
  return (u16)(r >> 16);
}

// (bf16(hi)<<16) | bf16(lo), RNE, single instruction
static __device__ __forceinline__ u32 cvtpk(float lo, float hi) {
  u32 r;
  asm("v_cvt_pk_bf16_f32 %0, %1, %2" : "=v"(r) : "v"(lo), "v"(hi));
  return r;
}

static __device__ __forceinline__ void barrier_lgkm() {
  asm volatile("s_waitcnt lgkmcnt(0)" ::: "memory");
  __builtin_amdgcn_s_barrier();
}

// ---------------- RMSNorm -> bf16 ----------------
__global__ __launch_bounds__(256) void k_rmsnorm(const float* __restrict__ x,
                                                 const float* __restrict__ w,
                                                 u16* __restrict__ xn) {
  int t = blockIdx.x, tid = threadIdx.x;
  const float* row = x + (size_t)t * HD;
  float4 v0 = ((const float4*)row)[tid*2+0];
  float4 v1 = ((const float4*)row)[tid*2+1];
  float ss = v0.x*v0.x+v0.y*v0.y+v0.z*v0.z+v0.w*v0.w
           + v1.x*v1.x+v1.y*v1.y+v1.z*v1.z+v1.w*v1.w;
  #pragma unroll
  for (int d=1; d<64; d<<=1) ss += __shfl_xor(ss, d);
  __shared__ float red[4];
  if ((tid&63)==0) red[tid>>6] = ss;
  __syncthreads();
  float rs = rsqrtf((red[0]+red[1]+red[2]+red[3]) * (1.0f/HD) + 1e-6f);
  const float* wp = w + tid*8;
  float a[8] = {v0.x,v0.y,v0.z,v0.w,v1.x,v1.y,v1.z,v1.w};
  uint4 o;
  o.x = (u32)f2bf(a[0]*rs*wp[0]) | ((u32)f2bf(a[1]*rs*wp[1])<<16);
  o.y = (u32)f2bf(a[2]*rs*wp[2]) | ((u32)f2bf(a[3]*rs*wp[3])<<16);
  o.z = (u32)f2bf(a[4]*rs*wp[4]) | ((u32)f2bf(a[5]*rs*wp[5])<<16);
  o.w = (u32)f2bf(a[6]*rs*wp[6]) | ((u32)f2bf(a[7]*rs*wp[7])<<16);
  ((uint4*)xn)[(size_t)t*(HD/8) + tid] = o;
}

// ---------------- Gate ----------------
__global__ __launch_bounds__(256) void k_gate(const float* __restrict__ x,
                                              const float* __restrict__ w,
                                              const float* __restrict__ gw,
                                              int* __restrict__ topk_id,
                                              float* __restrict__ topk_w,
                                              int* __restrict__ counts) {
  __shared__ float xs[HD];
  __shared__ float red[4];
  __shared__ float logits[NE];
  int t = blockIdx.x, tid = threadIdx.x;
  const float* row = x + (size_t)t*HD;
  float4 v0 = ((const float4*)row)[tid*2+0];
  float4 v1 = ((const float4*)row)[tid*2+1];
  float ss = v0.x*v0.x+v0.y*v0.y+v0.z*v0.z+v0.w*v0.w
           + v1.x*v1.x+v1.y*v1.y+v1.z*v1.z+v1.w*v1.w;
  #pragma unroll
  for (int d=1; d<64; d<<=1) ss += __shfl_xor(ss, d);
  if ((tid&63)==0) red[tid>>6] = ss;
  __syncthreads();
  float rs = 1.0f / sqrtf((red[0]+red[1]+red[2]+red[3]) * (1.0f/HD) + 1e-6f);
  const float* wp = w + tid*8;
  float a[8] = {v0.x,v0.y,v0.z,v0.w,v1.x,v1.y,v1.z,v1.w};
  #pragma unroll
  for (int j=0;j<8;++j) xs[tid*8+j] = a[j]*rs*wp[j];
  __syncthreads();
  int wave = tid>>6, lane = tid&63;
  for (int ei=0; ei<8; ++ei) {
    int e = wave*8 + ei;
    const float* g = gw + (size_t)e*HD;
    float s = 0.f;
    #pragma unroll
    for (int j=0;j<HD/64;++j) s += xs[lane + j*64] * g[lane + j*64];
    #pragma unroll
    for (int d=1; d<64; d<<=1) s += __shfl_xor(s, d);
    if (lane==0) logits[e] = s;
  }
  __syncthreads();
  if (tid==0) {
    float best[TOPK]; int bid[TOPK]; unsigned used = 0;
    for (int k2=0;k2<TOPK;++k2) {
      float bv = -1e30f; int bi = 0;
      for (int i2=0;i2<NE;++i2)
        if (!((used>>i2)&1u) && logits[i2] > bv) { bv = logits[i2]; bi = i2; }
      used |= 1u<<bi; best[k2] = bv; bid[k2] = bi;
    }
    float mx = best[0], sum = 0.f, wv[TOPK];
    for (int k2=0;k2<TOPK;++k2) { wv[k2] = expf(best[k2]-mx); sum += wv[k2]; }
    float inv = 1.f/sum;
    for (int k2=0;k2<TOPK;++k2) {
      topk_id[t*TOPK+k2] = bid[k2];
      topk_w[t*TOPK+k2] = wv[k2]*inv;
      atomicAdd(&counts[bid[k2]], 1);
    }
  }
}

__global__ void k_zero(int* counts, int* cursors) {
  int i = threadIdx.x;
  if (i < NE) { counts[i] = 0; cursors[i] = 0; }
}

__global__ void k_scan(const int* __restrict__ counts, int* __restrict__ starts) {
  if (threadIdx.x==0 && blockIdx.x==0) {
    int acc = 0;
    for (int e=0;e<NE;++e) { starts[e] = acc; acc += counts[e]; }
  }
}

__global__ __launch_bounds__(256) void k_dispatch(const int* __restrict__ topk_id,
                                                  const float* __restrict__ topk_w,
                                                  const int* __restrict__ starts,
                                                  int* __restrict__ cursors,
                                                  int* __restrict__ slot_tok,
                                                  float* __restrict__ slot_w) {
  int i = blockIdx.x*256 + threadIdx.x;
  int e = topk_id[i];
  int p = atomicAdd(&cursors[e], 1);
  int slot = starts[e] + p;
  slot_tok[slot] = i >> 2;
  slot_w[slot] = topk_w[i];
}

// ============ GEMM up (x @ [Wg|Wu]) + SwiGLU, fully reg-staged ============
// A (bf16 k-major): 16B slots, slot s: row=s>>2, phys kseg=s&3,
//   logical kseg = phys ^ ((row>>1)&3). Lane-linear writes (free), b128 reads 2-way.
// B (fp32 [k][n] -> bf16): col-major 8B units (4 ks), slot8 = col*8 + (q ^ ((col>>2)&7)).
//   Writes: XOR operand = t&7 varies per lane -> 2-way (free). Reads: 2x ds_read_b64
//   per frag, conflict-free. Staged cols interleave gate/up in 16-col groups.
template<bool INDEXED>
__global__ __launch_bounds__(256) void k_gemm_up(
    const u16* __restrict__ A, int lda, int kiter,
    const float* __restrict__ Bg, const float* __restrict__ Bu,
    size_t bstride, int ldb,
    const int* __restrict__ counts, const int* __restrict__ starts,
    const int* __restrict__ slot_tok,
    u16* __restrict__ actOut) {
  __shared__ u16 Al[2][4096];
  __shared__ u16 Bl[2][4096];
  __shared__ int rowL[128];
  int t = threadIdx.x;
  int n0 = blockIdx.x * 64;
  int m0 = blockIdx.y * 128;
  int e  = blockIdx.z;
  int M, rowbase;
  if (INDEXED) { M = counts[e]; rowbase = starts[e]; if (m0 >= M) return; }
  else { M = NTOK; rowbase = 0; }
  if (t < 128) {
    int m = m0 + t;
    rowL[t] = INDEXED ? slot_tok[rowbase + (m < M ? m : M-1)] : m;
  }
  __syncthreads();
  // A staging (slots t, t+256)
  int r0i = t>>2, r1i = r0i + 64;
  int segA = ((t&3) ^ ((r0i>>1)&3)) << 3;
  const u16* srcA0 = A + (size_t)rowL[r0i]*lda + segA;
  const u16* srcA1 = A + (size_t)rowL[r1i]*lda + segA;
  // B staging: thread covers staged cols sc4..sc4+3 at k-quad kb (ks kb*4..kb*4+3)
  int sc4 = (t&31)*4;
  int kb  = t>>5;
  int isup = (sc4>>4)&1;
  int srccol = n0 + ((sc4>>5)<<4) + (sc4&15);
  const float* bsrc = (isup ? Bu : Bg) + (INDEXED ? (size_t)e*bstride : 0)
                    + (size_t)(kb*4)*ldb + srccol;
  int bq4 = (kb ^ (t&7))*4;   // swizzled 8B-unit offset (in u16) within col block

  int lane = t&63, wave = t>>6, wr = wave>>1, wc = wave&1;
  int l15 = lane&15, l4 = lane>>4;
  int aoff[4], b0off[4], b1off[4];
  #pragma unroll
  for (int f=0; f<4; ++f) {
    int r = wr*64 + f*16 + l15;
    aoff[f] = r*32 + ((l4 ^ ((r>>1)&3))<<3);
    int c = wc*64 + f*16 + l15;
    int g = (c>>2)&7;
    b0off[f] = c*32 + (((2*l4)   ^ g)<<2);
    b1off[f] = c*32 + (((2*l4+1) ^ g)<<2);
  }
  f32x4 acc[4][4];
  #pragma unroll
  for (int fm=0;fm<4;++fm)
    #pragma unroll
    for (int fn=0;fn<4;++fn)
      acc[fm][fn] = (f32x4){0.f,0.f,0.f,0.f};

  // prologue: load + stage tile 0
  uint4 av0 = *(const uint4*)srcA0;
  uint4 av1 = *(const uint4*)srcA1;
  float4 bv[4];
  #pragma unroll
  for (int i=0;i<4;++i) bv[i] = *(const float4*)(bsrc + (size_t)i*ldb);
  srcA0 += 32; srcA1 += 32; bsrc += (size_t)32*ldb;
  *(uint4*)&Al[0][t*8] = av0;
  *(uint4*)&Al[0][2048 + t*8] = av1;
  {
    const float* f0 = (const float*)&bv[0];
    const float* f1 = (const float*)&bv[1];
    const float* f2 = (const float*)&bv[2];
    const float* f3 = (const float*)&bv[3];
    #pragma unroll
    for (int j=0;j<4;++j) {
      uint2 wv; wv.x = cvtpk(f0[j], f1[j]); wv.y = cvtpk(f2[j], f3[j]);
      *(uint2*)&Bl[0][(sc4+j)*32 + bq4] = wv;
    }
  }
  barrier_lgkm();

  int cur = 0;
  for (int kt = 0; kt < kiter; ++kt) {
    bool more = (kt+1 < kiter);
    uint4 avn0, avn1; float4 bvn[4];
    if (more) {
      avn0 = *(const uint4*)srcA0;
      avn1 = *(const uint4*)srcA1;
      #pragma unroll
      for (int i=0;i<4;++i) bvn[i] = *(const float4*)(bsrc + (size_t)i*ldb);
      srcA0 += 32; srcA1 += 32; bsrc += (size_t)32*ldb;
    }
    bf16x8 af[4], bfr[4];
    #pragma unroll
    for (int f=0; f<4; ++f) af[f] = *(const bf16x8*)&Al[cur][aoff[f]];
    #pragma unroll
    for (int f=0; f<4; ++f) {
      uint2 lo = *(const uint2*)&Bl[cur][b0off[f]];
      uint2 hi = *(const uint2*)&Bl[cur][b1off[f]];
      U32x4BF ub; ub.u = make_uint4(lo.x, lo.y, hi.x, hi.y);
      bfr[f] = ub.h;
    }
    #pragma unroll
    for (int fm=0; fm<4; ++fm)
      #pragma unroll
      for (int fn=0; fn<4; ++fn)
        acc[fm][fn] = __builtin_amdgcn_mfma_f32_16x16x32_bf16(af[fm], bfr[fn], acc[fm][fn], 0,0,0);
    if (more) {
      *(uint4*)&Al[cur^1][t*8] = avn0;
      *(uint4*)&Al[cur^1][2048 + t*8] = avn1;
      const float* f0 = (const float*)&bvn[0];
      const float* f1 = (const float*)&bvn[1];
      const float* f2 = (const float*)&bvn[2];
      const float* f3 = (const float*)&bvn[3];
      #pragma unroll
      for (int j=0;j<4;++j) {
        uint2 wv; wv.x = cvtpk(f0[j], f1[j]); wv.y = cvtpk(f2[j], f3[j]);
        *(uint2*)&Bl[cur^1][(sc4+j)*32 + bq4] = wv;
      }
    }
    cur ^= 1;
    barrier_lgkm();
  }
  // epilogue: SwiGLU on (gate,up) fragment pairs
  #pragma unroll
  for (int fm=0; fm<4; ++fm) {
    #pragma unroll
    for (int fq=0; fq<2; ++fq) {
      f32x4 g = acc[fm][2*fq], u = acc[fm][2*fq+1];
      int col = n0 + (wc*2+fq)*16 + l15;
      #pragma unroll
      for (int r=0;r<4;++r) {
        int mloc = wr*64 + fm*16 + l4*4 + r;
        int m = m0 + mloc;
        if (m < M) {
          float gv = g[r];
          float av = gv / (1.f + expf(-gv)) * u[r];
          actOut[(size_t)(rowbase+m)*ID + col] = f2bf(av);
        }
      }
    }
  }
}

// ============ GEMM down (act @ W2), fully reg-staged ============
template<bool INDEXED>
__global__ __launch_bounds__(256) void k_gemm_down(
    const u16* __restrict__ A, int lda, int kiter,
    const float* __restrict__ B, size_t bstride, int ldb,
    const int* __restrict__ counts, const int* __restrict__ starts,
    const int* __restrict__ slot_tok, const float* __restrict__ slot_w,
    const float* __restrict__ resid,
    float* __restrict__ out) {
  __shared__ u16 Al[2][4096];
  __shared__ u16 Bl[2][4096];
  __shared__ int tokL[128];
  __shared__ float wL[128];
  int t = threadIdx.x;
  int n0 = blockIdx.x * 128;
  int m0 = blockIdx.y * 128;
  int e  = blockIdx.z;
  int M, rowbase;
  if (INDEXED) { M = counts[e]; rowbase = starts[e]; if (m0 >= M) return; }
  else { M = NTOK; rowbase = 0; }
  if (INDEXED && t < 128) {
    int m = m0 + t;
    tokL[t] = (m<M) ? slot_tok[rowbase+m] : 0;
    wL[t]   = (m<M) ? slot_w[rowbase+m]  : 0.f;
  }
  if (INDEXED) __syncthreads();
  int r0i = t>>2, r1i = r0i + 64;
  int segA = ((t&3) ^ ((r0i>>1)&3)) << 3;
  int am0 = m0 + r0i, am1 = m0 + r1i;
  const u16* srcA0 = A + (size_t)(rowbase + (am0 < M ? am0 : M-1))*lda + segA;
  const u16* srcA1 = A + (size_t)(rowbase + (am1 < M ? am1 : M-1))*lda + segA;
  int sc4 = (t&31)*4;
  int kb  = t>>5;
  const float* bsrc = B + (INDEXED ? (size_t)e*bstride : 0)
                    + (size_t)(kb*4)*ldb + (n0 + sc4);
  int bq4 = (kb ^ (t&7))*4;

  int lane = t&63, wave = t>>6, wr = wave>>1, wc = wave&1;
  int l15 = lane&15, l4 = lane>>4;
  int aoff[4], b0off[4], b1off[4];
  #pragma unroll
  for (int f=0; f<4; ++f) {
    int r = wr*64 + f*16 + l15;
    aoff[f] = r*32 + ((l4 ^ ((r>>1)&3))<<3);
    int c = wc*64 + f*16 + l15;
    int g = (c>>2)&7;
    b0off[f] = c*32 + (((2*l4)   ^ g)<<2);
    b1off[f] = c*32 + (((2*l4+1) ^ g)<<2);
  }
  f32x4 acc[4][4];
  #pragma unroll
  for (int fm=0;fm<4;++fm)
    #pragma unroll
    for (int fn=0;fn<4;++fn)
      acc[fm][fn] = (f32x4){0.f,0.f,0.f,0.f};

  uint4 av0 = *(const uint4*)srcA0;
  uint4 av1 = *(const uint4*)srcA1;
  float4 bv[4];
  #pragma unroll
  for (int i=0;i<4;++i) bv[i] = *(const float4*)(bsrc + (size_t)i*ldb);
  srcA0 += 32; srcA1 += 32; bsrc += (size_t)32*ldb;
  *(uint4*)&Al[0][t*8] = av0;
  *(uint4*)&Al[0][2048 + t*8] = av1;
  {
    const float* f0 = (const float*)&bv[0];
    const float* f1 = (const float*)&bv[1];
    const float* f2 = (const float*)&bv[2];
    const float* f3 = (const float*)&bv[3];
    #pragma unroll
    for (int j=0;j<4;++j) {
      uint2 wv; wv.x = cvtpk(f0[j], f1[j]); wv.y = cvtpk(f2[j], f3[j]);
      *(uint2*)&Bl[0][(sc4+j)*32 + bq4] = wv;
    }
  }
  barrier_lgkm();

  int cur = 0;
  for (int kt = 0; kt < kiter; ++kt) {
    bool more = (kt+1 < kiter);
    uint4 avn0, avn1; float4 bvn[4];
    if (more) {
      avn0 = *(const uint4*)srcA0;
      avn1 = *(const uint4*)srcA1;
      #pragma unroll
      for (int i=0;i<4;++i) bvn[i] = *(const float4*)(bsrc + (size_t)i*ldb);
      srcA0 += 32; srcA1 += 32; bsrc += (size_t)32*ldb;
    }
    bf16x8 af[4], bfr[4];
    #pragma unroll
    for (int f=0; f<4; ++f) af[f] = *(const bf16x8*)&Al[cur][aoff[f]];
    #pragma unroll
    for (int f=0; f<4; ++f) {
      uint2 lo = *(const uint2*)&Bl[cur][b0off[f]];
      uint2 hi = *(const uint2*)&Bl[cur][b1off[f]];
      U32x4BF ub; ub.u = make_uint4(lo.x, lo.y, hi.x, hi.y);
      bfr[f] = ub.h;
    }
    #pragma unroll
    for (int fm=0; fm<4; ++fm)
      #pragma unroll
      for (int fn=0; fn<4; ++fn)
        acc[fm][fn] = __builtin_amdgcn_mfma_f32_16x16x32_bf16(af[fm], bfr[fn], acc[fm][fn], 0,0,0);
    if (more) {
      *(uint4*)&Al[cur^1][t*8] = avn0;
      *(uint4*)&Al[cur^1][2048 + t*8] = avn1;
      const float* f0 = (const float*)&bvn[0];
      const float* f1 = (const float*)&bvn[1];
      const float* f2 = (const float*)&bvn[2];
      const float* f3 = (const float*)&bvn[3];
      #pragma unroll
      for (int j=0;j<4;++j) {
        uint2 wv; wv.x = cvtpk(f0[j], f1[j]); wv.y = cvtpk(f2[j], f3[j]);
        *(uint2*)&Bl[cur^1][(sc4+j)*32 + bq4] = wv;
      }
    }
    cur ^= 1;
    barrier_lgkm();
  }
  #pragma unroll
  for (int fm=0; fm<4; ++fm) {
    #pragma unroll
    for (int fn=0; fn<4; ++fn) {
      f32x4 v = acc[fm][fn];
      int col = n0 + wc*64 + fn*16 + l15;
      #pragma unroll
      for (int r=0;r<4;++r) {
        int mloc = wr*64 + fm*16 + l4*4 + r;
        int m = m0 + mloc;
        if (m < M) {
          if (INDEXED) {
            atomicAdd(&out[(size_t)tokL[mloc]*HD + col], v[r]*wL[mloc]);
          } else {
            size_t o = (size_t)m*HD + col;
            out[o] = resid[o] + v[r];
          }
        }
      }
    }
  }
}

extern "C" void kernel_launch(void* const* d_in, const int* in_sizes, int n_in,
                              void* d_out, int out_size, void* d_ws, size_t ws_size,
                              hipStream_t stream) {
  const float* x    = (const float*)d_in[0];
  const float* nw   = (const float*)d_in[1];
  const float* gw   = (const float*)d_in[2];
  const float* w13  = (const float*)d_in[3];
  const float* w2   = (const float*)d_in[4];
  const float* sgw  = (const float*)d_in[5];
  const float* suw  = (const float*)d_in[6];
  const float* sdw  = (const float*)d_in[7];
  float* out = (float*)d_out;

  char* p = (char*)d_ws;
  u16* xn   = (u16*)p;  p += (size_t)NTOK*HD*2;
  u16* act  = (u16*)p;  p += (size_t)NSLOT*ID*2;
  u16* sact = (u16*)p;  p += (size_t)NTOK*ID*2;
  int*   topk_id  = (int*)p;   p += (size_t)NTOK*TOPK*4;
  float* topk_w   = (float*)p; p += (size_t)NTOK*TOPK*4;
  int*   slot_tok = (int*)p;   p += (size_t)NSLOT*4;
  float* slot_w   = (float*)p; p += (size_t)NSLOT*4;
  int*   counts   = (int*)p;   p += 64*4;
  int*   cursors  = (int*)p;   p += 64*4;
  int*   starts   = (int*)p;   p += 64*4;

  k_zero<<<1, 64, 0, stream>>>(counts, cursors);
  k_rmsnorm<<<NTOK, 256, 0, stream>>>(x, nw, xn);
  k_gate<<<NTOK, 256, 0, stream>>>(x, nw, gw, topk_id, topk_w, counts);
  k_scan<<<1, 1, 0, stream>>>(counts, starts);
  k_dispatch<<<NSLOT/256, 256, 0, stream>>>(topk_id, topk_w, starts, cursors, slot_tok, slot_w);

  // routed up-proj + swiglu (B = w13 fp32, gate cols [0,I), up cols [I,2I))
  k_gemm_up<true><<<dim3(ID/64, 8, NE), 256, 0, stream>>>(
      xn, HD, HD/32, w13, w13 + ID, (size_t)HD*2*ID, 2*ID,
      counts, starts, slot_tok, act);
  // shared up-proj + swiglu
  k_gemm_up<false><<<dim3(ID/64, NTOK/128, 1), 256, 0, stream>>>(
      xn, HD, HD/32, sgw, suw, 0, ID, nullptr, nullptr, nullptr, sact);
  // shared down-proj: out = residual + shared
  k_gemm_down<false><<<dim3(HD/128, NTOK/128, 1), 256, 0, stream>>>(
      sact, ID, ID/32, sdw, 0, HD, nullptr, nullptr, nullptr, nullptr, x, out);
  // routed down-proj: atomic weighted scatter-add into out
  k_gemm_down<true><<<dim3(HD/128, 8, NE), 256, 0, stream>>>(
      act, ID, ID/32, w2, (size_t)ID*HD, HD, counts, starts, slot_tok, slot_w, nullptr, out);
}